// Round 1
// baseline (437.728 us; speedup 1.0000x reference)
//
#include <hip/hip_runtime.h>
#include <hip/hip_bf16.h>

// Integrate-and-fire over T=4 timesteps.
// x: [T*B, C, H, W] fp32 = [4, 16777216] after folding spatial dims.
// thresh: scalar (8.0). mem0 = 0.5*thre.
// per t: mem += x[t]; spike = (mem - thre >= 0) ? thre : 0; mem -= spike; out[t] = spike.
// Memory-bound: 256 MiB in + 256 MiB out. One thread per float4 column,
// temporal chain kept in registers.

#define T_STEPS 4

__global__ __launch_bounds__(256) void if_spike_kernel(
    const float4* __restrict__ x,
    const float* __restrict__ thresh,
    float4* __restrict__ out,
    long n_per_t_vec)  // elements per timestep, in float4 units
{
    long idx = (long)blockIdx.x * blockDim.x + threadIdx.x;
    if (idx >= n_per_t_vec) return;

    const float thre = thresh[0];
    float4 mem;
    mem.x = 0.5f * thre;
    mem.y = 0.5f * thre;
    mem.z = 0.5f * thre;
    mem.w = 0.5f * thre;

#pragma unroll
    for (int t = 0; t < T_STEPS; ++t) {
        float4 xt = x[(long)t * n_per_t_vec + idx];
        float4 spike;

        mem.x += xt.x;
        spike.x = (mem.x >= thre) ? thre : 0.0f;
        mem.x -= spike.x;

        mem.y += xt.y;
        spike.y = (mem.y >= thre) ? thre : 0.0f;
        mem.y -= spike.y;

        mem.z += xt.z;
        spike.z = (mem.z >= thre) ? thre : 0.0f;
        mem.z -= spike.z;

        mem.w += xt.w;
        spike.w = (mem.w >= thre) ? thre : 0.0f;
        mem.w -= spike.w;

        out[(long)t * n_per_t_vec + idx] = spike;
    }
}

extern "C" void kernel_launch(void* const* d_in, const int* in_sizes, int n_in,
                              void* d_out, int out_size, void* d_ws, size_t ws_size,
                              hipStream_t stream) {
    const float* x = (const float*)d_in[0];
    const float* thresh = (const float*)d_in[1];
    float* out = (float*)d_out;

    // out_size = T*B*C*H*W = 67108864; per-timestep elements = out_size / T
    long n_per_t = (long)out_size / T_STEPS;       // 16777216, divisible by 4
    long n_per_t_vec = n_per_t / 4;                // 4194304 float4s

    const int block = 256;
    long grid = (n_per_t_vec + block - 1) / block; // 16384 blocks

    if_spike_kernel<<<(dim3)(unsigned)grid, block, 0, stream>>>(
        (const float4*)x, thresh, (float4*)out, n_per_t_vec);
}

// Round 2
// 421.297 us; speedup vs baseline: 1.0390x; 1.0390x over previous
//
#include <hip/hip_runtime.h>
#include <hip/hip_bf16.h>

// Integrate-and-fire over T=4 timesteps.
// x: [T*B, C, H, W] fp32 = [4, 16777216] after folding spatial dims.
// thresh: scalar (8.0). mem0 = 0.5*thre.
// per t: mem += x[t]; spike = (mem >= thre) ? thre : 0; mem -= spike; out[t] = spike.
// Memory-bound: 268 MB in + 268 MB out, read-once / write-once streams.
// Nontemporal load/store hints to avoid L2/L3 write-allocate churn.

#define T_STEPS 4

typedef float f4 __attribute__((ext_vector_type(4)));

__global__ __launch_bounds__(256) void if_spike_kernel(
    const f4* __restrict__ x,
    const float* __restrict__ thresh,
    f4* __restrict__ out,
    long n_per_t_vec)  // elements per timestep, in float4 units
{
    long idx = (long)blockIdx.x * blockDim.x + threadIdx.x;
    if (idx >= n_per_t_vec) return;

    const float thre = thresh[0];

    // Issue all 4 temporal loads up front (independent), nontemporal.
    f4 xt[T_STEPS];
#pragma unroll
    for (int t = 0; t < T_STEPS; ++t) {
        xt[t] = __builtin_nontemporal_load(&x[(long)t * n_per_t_vec + idx]);
    }

    f4 mem = {0.5f * thre, 0.5f * thre, 0.5f * thre, 0.5f * thre};

#pragma unroll
    for (int t = 0; t < T_STEPS; ++t) {
        f4 spike;
        mem += xt[t];
        spike.x = (mem.x >= thre) ? thre : 0.0f;
        spike.y = (mem.y >= thre) ? thre : 0.0f;
        spike.z = (mem.z >= thre) ? thre : 0.0f;
        spike.w = (mem.w >= thre) ? thre : 0.0f;
        mem -= spike;
        __builtin_nontemporal_store(spike, &out[(long)t * n_per_t_vec + idx]);
    }
}

extern "C" void kernel_launch(void* const* d_in, const int* in_sizes, int n_in,
                              void* d_out, int out_size, void* d_ws, size_t ws_size,
                              hipStream_t stream) {
    const float* x = (const float*)d_in[0];
    const float* thresh = (const float*)d_in[1];
    float* out = (float*)d_out;

    long n_per_t = (long)out_size / T_STEPS;       // 16777216
    long n_per_t_vec = n_per_t / 4;                // 4194304 float4s

    const int block = 256;
    long grid = (n_per_t_vec + block - 1) / block; // 16384 blocks

    if_spike_kernel<<<(dim3)(unsigned)grid, block, 0, stream>>>(
        (const f4*)x, thresh, (f4*)out, n_per_t_vec);
}